// Round 5
// baseline (800.223 us; speedup 1.0000x reference)
//
#include <hip/hip_runtime.h>
#include <math.h>

#define IN_DIM 128
#define HID 64
#define NPB 128            // nodes per bucket
#define NPB_SH 7
#define CAP 4096           // pairs capacity per bucket (mean 2048, sigma~45)
#define OVFCAP 8192
#define CHUNK 8192         // edges per binning block

typedef __attribute__((ext_vector_type(8))) short bf16x8;
typedef __attribute__((ext_vector_type(4))) float f32x4;
typedef __attribute__((ext_vector_type(4))) _Float16 f16x4;

static __device__ inline short f2bf(float f) {
    unsigned u = __float_as_uint(f);
    u += 0x7fff + ((u >> 16) & 1);          // RNE
    return (short)(u >> 16);
}

// dis[i] = rsqrt(cnt[i] + 1)   (+1 = self-loop)
__global__ void k_dis(const int* __restrict__ cnt, float* __restrict__ dis, int n) {
    int i = blockIdx.x * blockDim.x + threadIdx.x;
    if (i < n) dis[i] = rsqrtf((float)(cnt[i] + 1));
}

// ------- pack W1 [128][64] f32 -> bf16 MFMA B-fragment order -------------
__global__ void k_packW(const float* __restrict__ W1, ushort* __restrict__ W1p) {
    int idx = blockIdx.x * 256 + threadIdx.x;        // 0..8191
    int i = idx & 7, lane = (idx >> 3) & 63, fb = (idx >> 9) & 3, kc = (idx >> 11) & 3;
    int k = kc * 32 + (lane >> 4) * 8 + i;
    int f = fb * 16 + (lane & 15);
    W1p[idx] = (ushort)f2bf(W1[k * HID + f]);
}

// ---- binning: edges -> bucket-grouped packed pairs, + degree count ------
// LDS counting-sort per block so global writes are coalesced bursts.
__global__ void __launch_bounds__(1024) k_binpairs(
        const int* __restrict__ row, const int* __restrict__ col,
        int* __restrict__ cnt, unsigned* __restrict__ bCur,
        unsigned* __restrict__ pairs, unsigned* __restrict__ gOvf,
        unsigned* __restrict__ ovfPk, unsigned* __restrict__ ovfB,
        int E, int nbuk) {
    __shared__ unsigned cntL[1024];
    __shared__ unsigned scanA[1024];
    __shared__ unsigned baseG[1024];
    __shared__ unsigned stage[CHUNK];
    __shared__ unsigned short bidA[CHUNK];

    int t = threadIdx.x;
    int base = blockIdx.x * CHUNK;
    int cc = min(CHUNK, E - base);

    cntL[t] = 0;
    __syncthreads();

    unsigned myPk[8];
    unsigned short myB[8], myR[8];
#pragma unroll
    for (int i = 0; i < 8; ++i) {
        int j = i * 1024 + t;
        myB[i] = 0xFFFFu;
        if (j < cc) {
            int e = base + j;
            int r = row[e], c = col[e];
            atomicAdd(&cnt[c], 1);
            int b = c >> NPB_SH;
            unsigned rk = atomicAdd(&cntL[b], 1u);
            myPk[i] = (unsigned)r | ((unsigned)(c & (NPB - 1)) << 24);
            myB[i] = (unsigned short)b;
            myR[i] = (unsigned short)rk;
        }
    }
    __syncthreads();
    // reserve global segment space per bucket
    if (t < nbuk && cntL[t] > 0) baseG[t] = atomicAdd(&bCur[t], cntL[t]);
    // inclusive scan of counts
    scanA[t] = cntL[t];
    __syncthreads();
    for (int off = 1; off < 1024; off <<= 1) {
        unsigned v = (t >= off) ? scanA[t - off] : 0u;
        __syncthreads();
        scanA[t] += v;
        __syncthreads();
    }
    // place into LDS stage, grouped by bucket
#pragma unroll
    for (int i = 0; i < 8; ++i) {
        if (myB[i] != 0xFFFFu) {
            int b = myB[i];
            unsigned pos = scanA[b] - cntL[b] + myR[i];
            stage[pos] = myPk[i];
            bidA[pos] = (unsigned short)b;
        }
    }
    __syncthreads();
    // stream out: consecutive threads -> mostly-consecutive global addresses
    for (int j = t; j < cc; j += 1024) {
        int b = bidA[j];
        unsigned excl = scanA[b] - cntL[b];
        unsigned pos = baseG[b] + ((unsigned)j - excl);
        if (pos < CAP) {
            pairs[(size_t)b * CAP + pos] = stage[j];
        } else {
            unsigned oi = atomicAdd(gOvf, 1u);
            if (oi < OVFCAP) { ovfPk[oi] = stage[j]; ovfB[oi] = (unsigned)b; }
        }
    }
}

// ------- h1s = (x @ W1) * dis[node]  via bf16 MFMA, fp16 output ----------
__global__ void __launch_bounds__(256) k_gemm1(const float* __restrict__ x,
                                               const ushort* __restrict__ W1p,
                                               const float* __restrict__ dis,
                                               _Float16* __restrict__ h1s, int n) {
    int t = threadIdx.x, wave = t >> 6, lane = t & 63;
    int nb = blockIdx.x * 64 + wave * 16;
    int arow = nb + (lane & 15);            // A: row = lane&15
    int g = lane >> 4;                      // k-group
    const bf16x8* Wp = (const bf16x8*)W1p;

    f32x4 acc0 = {0.f, 0.f, 0.f, 0.f}, acc1 = acc0, acc2 = acc0, acc3 = acc0;

#pragma unroll
    for (int kc = 0; kc < 4; ++kc) {
        bf16x8 a;
        if (arow < n) {
            const float4* xp = (const float4*)(x + (size_t)arow * IN_DIM + kc * 32 + g * 8);
            float4 x0 = xp[0], x1 = xp[1];
            a[0] = f2bf(x0.x); a[1] = f2bf(x0.y); a[2] = f2bf(x0.z); a[3] = f2bf(x0.w);
            a[4] = f2bf(x1.x); a[5] = f2bf(x1.y); a[6] = f2bf(x1.z); a[7] = f2bf(x1.w);
        } else {
            for (int i = 0; i < 8; ++i) a[i] = 0;
        }
        acc0 = __builtin_amdgcn_mfma_f32_16x16x32_bf16(a, Wp[(kc * 4 + 0) * 64 + lane], acc0, 0, 0, 0);
        acc1 = __builtin_amdgcn_mfma_f32_16x16x32_bf16(a, Wp[(kc * 4 + 1) * 64 + lane], acc1, 0, 0, 0);
        acc2 = __builtin_amdgcn_mfma_f32_16x16x32_bf16(a, Wp[(kc * 4 + 2) * 64 + lane], acc2, 0, 0, 0);
        acc3 = __builtin_amdgcn_mfma_f32_16x16x32_bf16(a, Wp[(kc * 4 + 3) * 64 + lane], acc3, 0, 0, 0);
    }

    // D: col = lane&15, row = (lane>>4)*4 + reg
    int c = lane & 15, rbase = g * 4;
    float dn[4];
    int nd[4];
#pragma unroll
    for (int r = 0; r < 4; ++r) {
        nd[r] = nb + rbase + r;
        dn[r] = (nd[r] < n) ? dis[nd[r]] : 0.f;
    }
#define EPI(FB, ACC)                                                          \
    {                                                                         \
        int f = FB * 16 + c;                                                  \
        _Pragma("unroll") for (int r = 0; r < 4; ++r) {                       \
            if (nd[r] < n)                                                    \
                h1s[(size_t)nd[r] * HID + f] = (_Float16)(ACC[r] * dn[r]);    \
        }                                                                     \
    }
    EPI(0, acc0) EPI(1, acc1) EPI(2, acc2) EPI(3, acc3)
#undef EPI
}

// ---- layer-1 bucket aggregation in LDS + tanh + W2 epilogue -> es -------
__global__ void __launch_bounds__(1024) k_pass2(
        const unsigned* __restrict__ pairs, const unsigned* __restrict__ bCur,
        const _Float16* __restrict__ h1s, const float* __restrict__ dis,
        const float* __restrict__ b1, const float* __restrict__ W2,
        const unsigned* __restrict__ gOvf, const unsigned* __restrict__ ovfPk,
        const unsigned* __restrict__ ovfB,
        float* __restrict__ es, int n) {
    __shared__ float aggL[NPB * 65];        // stride 65: bank-conflict relief
    int t = threadIdx.x;
    int b = blockIdx.x;
    for (int i = t; i < NPB * 65; i += 1024) aggL[i] = 0.f;
    __syncthreads();

    int cb = (int)min(bCur[b], (unsigned)CAP);
    const unsigned* seg = pairs + (size_t)b * CAP;
    int gid = t >> 4, sub = t & 15;         // 64 edge-groups x 16 feature-lanes

    int i = gid;
    unsigned pk = (i < cb) ? seg[i] : 0u;
    while (i < cb) {
        int inext = i + 64;
        unsigned pkn = (inext < cb) ? seg[inext] : 0u;   // prefetch
        unsigned src = pk & 0xFFFFFFu;
        unsigned dl = pk >> 24;
        f16x4 v = *(const f16x4*)(h1s + (size_t)src * HID + sub * 4);
        float* ap = &aggL[dl * 65 + sub * 4];
        atomicAdd(&ap[0], (float)v[0]);
        atomicAdd(&ap[1], (float)v[1]);
        atomicAdd(&ap[2], (float)v[2]);
        atomicAdd(&ap[3], (float)v[3]);
        pk = pkn; i = inext;
    }
    // overflow entries (normally zero)
    unsigned m = *gOvf;
    if (m > OVFCAP) m = OVFCAP;
    for (unsigned o = t; o < m; o += 1024) {
        if (ovfB[o] == (unsigned)b) {
            unsigned pk2 = ovfPk[o];
            unsigned src = pk2 & 0xFFFFFFu;
            unsigned dl = pk2 >> 24;
            for (int f4 = 0; f4 < 16; ++f4) {
                f16x4 v = *(const f16x4*)(h1s + (size_t)src * HID + f4 * 4);
                float* ap = &aggL[dl * 65 + f4 * 4];
                for (int jj = 0; jj < 4; ++jj) atomicAdd(&ap[jj], (float)v[jj]);
            }
        }
    }
    __syncthreads();

    // epilogue: 8 threads per node, each 8 features
    int node = t >> 3, q = t & 7;
    int nd = b * NPB + node;
    float s0 = 0.f, s1 = 0.f, d = 0.f;
    if (nd < n) {
        d = dis[nd];
        for (int f = q * 8; f < q * 8 + 8; ++f) {
            float a = aggL[node * 65 + f] + (float)h1s[(size_t)nd * HID + f]; // + self
            float v = tanhf(fmaf(a, d, b1[f]));
            s0 = fmaf(v, W2[f * 2 + 0], s0);
            s1 = fmaf(v, W2[f * 2 + 1], s1);
        }
    }
    s0 += __shfl_xor(s0, 1); s1 += __shfl_xor(s1, 1);
    s0 += __shfl_xor(s0, 2); s1 += __shfl_xor(s1, 2);
    s0 += __shfl_xor(s0, 4); s1 += __shfl_xor(s1, 4);
    if (nd < n && q == 0) {
        es[nd * 2 + 0] = s0 * d;            // pre-scaled by dis for layer-2
        es[nd * 2 + 1] = s1 * d;
    }
}

// ---- layer-2 bucket aggregation + tanh + classifier + sigmoid -----------
__global__ void __launch_bounds__(256) k_pass2b(
        const unsigned* __restrict__ pairs, const unsigned* __restrict__ bCur,
        const float* __restrict__ es, const float* __restrict__ dis,
        const float* __restrict__ b2, const float* __restrict__ Wc,
        const float* __restrict__ bc,
        const unsigned* __restrict__ gOvf, const unsigned* __restrict__ ovfPk,
        const unsigned* __restrict__ ovfB,
        float* __restrict__ out, int n) {
    __shared__ float a2[NPB][2];
    int t = threadIdx.x, b = blockIdx.x;
    for (int i = t; i < NPB * 2; i += 256) ((float*)a2)[i] = 0.f;
    __syncthreads();
    int cb = (int)min(bCur[b], (unsigned)CAP);
    const unsigned* seg = pairs + (size_t)b * CAP;
    for (int i = t; i < cb; i += 256) {
        unsigned pk = seg[i];
        unsigned src = pk & 0xFFFFFFu, dl = pk >> 24;
        float2 v = *(const float2*)(es + (size_t)src * 2);
        atomicAdd(&a2[dl][0], v.x);
        atomicAdd(&a2[dl][1], v.y);
    }
    unsigned m = *gOvf;
    if (m > OVFCAP) m = OVFCAP;
    for (unsigned o = t; o < m; o += 256) {
        if (ovfB[o] == (unsigned)b) {
            unsigned pk = ovfPk[o];
            unsigned src = pk & 0xFFFFFFu, dl = pk >> 24;
            float2 v = *(const float2*)(es + (size_t)src * 2);
            atomicAdd(&a2[dl][0], v.x);
            atomicAdd(&a2[dl][1], v.y);
        }
    }
    __syncthreads();
    int nd = b * NPB + t;
    if (t < NPB && nd < n) {
        float d = dis[nd];
        float2 self = *(const float2*)(es + (size_t)nd * 2);
        float e0 = tanhf(fmaf(a2[t][0] + self.x, d, b2[0]));
        float e1 = tanhf(fmaf(a2[t][1] + self.y, d, b2[1]));
        float z = fmaf(e0, Wc[0], fmaf(e1, Wc[1], bc[0]));
        out[nd] = 1.f / (1.f + expf(-z));
    }
}

extern "C" void kernel_launch(void* const* d_in, const int* in_sizes, int n_in,
                              void* d_out, int out_size, void* d_ws, size_t ws_size,
                              hipStream_t stream) {
    const float* x  = (const float*)d_in[0];
    const int*   ei = (const int*)d_in[1];   // [2, E] as int32
    const float* W1 = (const float*)d_in[2];
    const float* b1 = (const float*)d_in[3];
    const float* W2 = (const float*)d_in[4];
    const float* b2 = (const float*)d_in[5];
    const float* Wc = (const float*)d_in[6];
    const float* bc = (const float*)d_in[7];

    const int n = in_sizes[0] / IN_DIM;
    const int E = in_sizes[1] / 2;
    const int* row = ei;
    const int* col = ei + E;
    const int nbuk = (n + NPB - 1) / NPB;    // 782 for n=100000 (must be <=1024)

    // workspace layout, 512B-aligned slices; cnt/bCur/gOvf adjacent -> one memset
    char* w = (char*)d_ws;
    auto alloc = [&](size_t bytes) {
        char* p = w;
        w += (bytes + 511) & ~(size_t)511;
        return p;
    };
    int*      cnt   = (int*)alloc((size_t)n * 4 + (size_t)nbuk * 4 + 4 + 8);
    unsigned* bCur  = (unsigned*)(cnt + n);
    unsigned* gOvf  = bCur + nbuk;
    float*    dis   = (float*)alloc((size_t)n * 4);
    ushort*   W1p   = (ushort*)alloc(16 * 64 * 8 * 2);
    unsigned* ovfPk = (unsigned*)alloc((size_t)OVFCAP * 4);
    unsigned* ovfB  = (unsigned*)alloc((size_t)OVFCAP * 4);
    unsigned* pairs = (unsigned*)alloc((size_t)nbuk * CAP * 4);
    _Float16* h1s   = (_Float16*)alloc((size_t)n * HID * 2);
    float*    es    = (float*)alloc((size_t)n * 2 * 4);

    hipMemsetAsync(cnt, 0, ((size_t)n + nbuk + 1) * 4, stream);

    k_binpairs<<<(E + CHUNK - 1) / CHUNK, 1024, 0, stream>>>(
        row, col, cnt, bCur, pairs, gOvf, ovfPk, ovfB, E, nbuk);
    k_dis<<<(n + 255) / 256, 256, 0, stream>>>(cnt, dis, n);
    k_packW<<<32, 256, 0, stream>>>(W1, W1p);
    k_gemm1<<<(n + 63) / 64, 256, 0, stream>>>(x, W1p, dis, h1s, n);
    k_pass2<<<nbuk, 1024, 0, stream>>>(pairs, bCur, h1s, dis, b1, W2,
                                       gOvf, ovfPk, ovfB, es, n);
    k_pass2b<<<nbuk, 256, 0, stream>>>(pairs, bCur, es, dis, b2, Wc, bc,
                                       gOvf, ovfPk, ovfB, (float*)d_out, n);
}

// Round 6
// 175.983 us; speedup vs baseline: 4.5472x; 4.5472x over previous
//
#include <hip/hip_runtime.h>
#include <math.h>

#define IN_DIM 128
#define HID 64
#define NPB 128            // nodes per bucket
#define NPB_SH 7
#define CAP 4096           // pairs capacity per bucket (mean 2048, ~45 sigma headroom)
#define OVFCAP 8192
#define CHUNK 8192         // edges per binning block

typedef __attribute__((ext_vector_type(8))) short bf16x8;
typedef __attribute__((ext_vector_type(4))) float f32x4;
typedef __attribute__((ext_vector_type(4))) _Float16 f16x4;

static __device__ inline short f2bf(float f) {
    unsigned u = __float_as_uint(f);
    u += 0x7fff + ((u >> 16) & 1);          // RNE
    return (short)(u >> 16);
}

// dis[i] = rsqrt(cnt[i] + 1)   (+1 = self-loop)
__global__ void k_dis(const int* __restrict__ cnt, float* __restrict__ dis, int n) {
    int i = blockIdx.x * blockDim.x + threadIdx.x;
    if (i < n) dis[i] = rsqrtf((float)(cnt[i] + 1));
}

// ------- pack W1 [128][64] f32 -> bf16 MFMA B-fragment order -------------
__global__ void k_packW(const float* __restrict__ W1, ushort* __restrict__ W1p) {
    int idx = blockIdx.x * 256 + threadIdx.x;        // 0..8191
    int i = idx & 7, lane = (idx >> 3) & 63, fb = (idx >> 9) & 3, kc = (idx >> 11) & 3;
    int k = kc * 32 + (lane >> 4) * 8 + i;
    int f = fb * 16 + (lane & 15);
    W1p[idx] = (ushort)f2bf(W1[k * HID + f]);
}

// ---- binning: edges -> bucket-grouped packed pairs, + degree count ------
// LDS counting-sort per block so global writes are coalesced bursts.
__global__ void __launch_bounds__(1024) k_binpairs(
        const int* __restrict__ row, const int* __restrict__ col,
        int* __restrict__ cnt, unsigned* __restrict__ bCur,
        unsigned* __restrict__ pairs, unsigned* __restrict__ gOvf,
        unsigned* __restrict__ ovfPk, unsigned* __restrict__ ovfB,
        int E, int nbuk) {
    __shared__ unsigned cntL[1024];
    __shared__ unsigned scanA[1024];
    __shared__ unsigned baseG[1024];
    __shared__ unsigned stage[CHUNK];
    __shared__ unsigned short bidA[CHUNK];

    int t = threadIdx.x;
    int base = blockIdx.x * CHUNK;
    int cc = min(CHUNK, E - base);

    cntL[t] = 0;
    __syncthreads();

    unsigned myPk[8];
    unsigned short myB[8], myR[8];
#pragma unroll
    for (int i = 0; i < 8; ++i) {
        int j = i * 1024 + t;
        myB[i] = 0xFFFFu;
        if (j < cc) {
            int e = base + j;
            int r = row[e], c = col[e];
            atomicAdd(&cnt[c], 1);
            int b = c >> NPB_SH;
            unsigned rk = atomicAdd(&cntL[b], 1u);
            myPk[i] = (unsigned)r | ((unsigned)(c & (NPB - 1)) << 24);
            myB[i] = (unsigned short)b;
            myR[i] = (unsigned short)rk;
        }
    }
    __syncthreads();
    // reserve global segment space per bucket
    if (t < nbuk && cntL[t] > 0) baseG[t] = atomicAdd(&bCur[t], cntL[t]);
    // inclusive scan of counts
    scanA[t] = cntL[t];
    __syncthreads();
    for (int off = 1; off < 1024; off <<= 1) {
        unsigned v = (t >= off) ? scanA[t - off] : 0u;
        __syncthreads();
        scanA[t] += v;
        __syncthreads();
    }
    // place into LDS stage, grouped by bucket
#pragma unroll
    for (int i = 0; i < 8; ++i) {
        if (myB[i] != 0xFFFFu) {
            int b = myB[i];
            unsigned pos = scanA[b] - cntL[b] + myR[i];
            stage[pos] = myPk[i];
            bidA[pos] = (unsigned short)b;
        }
    }
    __syncthreads();
    // stream out: consecutive threads -> mostly-consecutive global addresses
    for (int j = t; j < cc; j += 1024) {
        int b = bidA[j];
        unsigned excl = scanA[b] - cntL[b];
        unsigned pos = baseG[b] + ((unsigned)j - excl);
        if (pos < CAP) {
            pairs[(size_t)b * CAP + pos] = stage[j];
        } else {
            unsigned oi = atomicAdd(gOvf, 1u);
            if (oi < OVFCAP) { ovfPk[oi] = stage[j]; ovfB[oi] = (unsigned)b; }
        }
    }
}

// ------- h1s = (x @ W1) * dis[node]  via bf16 MFMA, fp16 output ----------
__global__ void __launch_bounds__(256) k_gemm1(const float* __restrict__ x,
                                               const ushort* __restrict__ W1p,
                                               const float* __restrict__ dis,
                                               _Float16* __restrict__ h1s, int n) {
    int t = threadIdx.x, wave = t >> 6, lane = t & 63;
    int nb = blockIdx.x * 64 + wave * 16;
    int arow = nb + (lane & 15);            // A: row = lane&15
    int g = lane >> 4;                      // k-group
    const bf16x8* Wp = (const bf16x8*)W1p;

    f32x4 acc0 = {0.f, 0.f, 0.f, 0.f}, acc1 = acc0, acc2 = acc0, acc3 = acc0;

#pragma unroll
    for (int kc = 0; kc < 4; ++kc) {
        bf16x8 a;
        if (arow < n) {
            const float4* xp = (const float4*)(x + (size_t)arow * IN_DIM + kc * 32 + g * 8);
            float4 x0 = xp[0], x1 = xp[1];
            a[0] = f2bf(x0.x); a[1] = f2bf(x0.y); a[2] = f2bf(x0.z); a[3] = f2bf(x0.w);
            a[4] = f2bf(x1.x); a[5] = f2bf(x1.y); a[6] = f2bf(x1.z); a[7] = f2bf(x1.w);
        } else {
            for (int i = 0; i < 8; ++i) a[i] = 0;
        }
        acc0 = __builtin_amdgcn_mfma_f32_16x16x32_bf16(a, Wp[(kc * 4 + 0) * 64 + lane], acc0, 0, 0, 0);
        acc1 = __builtin_amdgcn_mfma_f32_16x16x32_bf16(a, Wp[(kc * 4 + 1) * 64 + lane], acc1, 0, 0, 0);
        acc2 = __builtin_amdgcn_mfma_f32_16x16x32_bf16(a, Wp[(kc * 4 + 2) * 64 + lane], acc2, 0, 0, 0);
        acc3 = __builtin_amdgcn_mfma_f32_16x16x32_bf16(a, Wp[(kc * 4 + 3) * 64 + lane], acc3, 0, 0, 0);
    }

    // D: col = lane&15, row = (lane>>4)*4 + reg
    int c = lane & 15, rbase = g * 4;
    float dn[4];
    int nd[4];
#pragma unroll
    for (int r = 0; r < 4; ++r) {
        nd[r] = nb + rbase + r;
        dn[r] = (nd[r] < n) ? dis[nd[r]] : 0.f;
    }
#define EPI(FB, ACC)                                                          \
    {                                                                         \
        int f = FB * 16 + c;                                                  \
        _Pragma("unroll") for (int r = 0; r < 4; ++r) {                       \
            if (nd[r] < n)                                                    \
                h1s[(size_t)nd[r] * HID + f] = (_Float16)(ACC[r] * dn[r]);    \
        }                                                                     \
    }
    EPI(0, acc0) EPI(1, acc1) EPI(2, acc2) EPI(3, acc3)
#undef EPI
}

// ---- layer-1: LDS counting-sort by dst-local, then atomic-free gather ---
// one block = one bucket of 128 nodes; writes sorted pairs + offsets back.
__global__ void __launch_bounds__(1024) k_pass2(
        unsigned* __restrict__ pairs, const unsigned* __restrict__ bCur,
        const _Float16* __restrict__ h1s, const float* __restrict__ dis,
        const float* __restrict__ b1, const float* __restrict__ W2,
        const unsigned* __restrict__ gOvf, const unsigned* __restrict__ ovfPk,
        const unsigned* __restrict__ ovfB,
        float* __restrict__ es, unsigned* __restrict__ offsG, int n) {
    __shared__ unsigned stage[CAP];         // 16 KB
    __shared__ unsigned sorted[CAP];        // 16 KB
    __shared__ unsigned cntN[NPB];
    __shared__ unsigned offs[NPB + 1];
    __shared__ unsigned cur[NPB];
    __shared__ int cbS;

    int t = threadIdx.x, b = blockIdx.x;
    int cb = (int)min(bCur[b], (unsigned)CAP);
    if (t < NPB) cntN[t] = 0;
    unsigned* seg = pairs + (size_t)b * CAP;
    for (int i = t; i < cb; i += 1024) stage[i] = seg[i];
    if (t == 0) {                           // append overflow (normally none)
        int c = cb;
        unsigned m = *gOvf; if (m > OVFCAP) m = OVFCAP;
        for (unsigned o = 0; o < m && c < CAP; ++o)
            if (ovfB[o] == (unsigned)b) stage[c++] = ovfPk[o];
        cbS = c;
    }
    __syncthreads();
    int cbt = cbS;
    for (int i = t; i < cbt; i += 1024) atomicAdd(&cntN[stage[i] >> 24], 1u);
    __syncthreads();
    // exclusive scan over 128 bins (Hillis-Steele)
    if (t < NPB) offs[t + 1] = cntN[t];
    if (t == 0) offs[0] = 0;
    __syncthreads();
    for (int off = 1; off < NPB; off <<= 1) {
        unsigned v = 0;
        if (t < NPB && (int)t + 1 > off) v = offs[t + 1 - off];
        __syncthreads();
        if (t < NPB) offs[t + 1] += v;
        __syncthreads();
    }
    if (t < NPB) cur[t] = offs[t];
    __syncthreads();
    for (int i = t; i < cbt; i += 1024) {
        unsigned pk = stage[i];
        unsigned pos = atomicAdd(&cur[pk >> 24], 1u);
        sorted[pos] = pk;
    }
    __syncthreads();
    // write back sorted pairs + offsets (coalesced) for the layer-2 pass
    for (int i = t; i < cbt; i += 1024) seg[i] = sorted[i];
    if (t <= NPB) offsG[(size_t)b * (NPB + 1) + t] = offs[t];

    // gather: 16 waves x 8 nodes; 4 edge-groups x 16 feature-lanes per wave
    int wave = t >> 6, lane = t & 63;
    int grp = lane >> 4, sub = lane & 15;
    float4 bb  = *(const float4*)(b1 + sub * 4);
    float4 w01 = *(const float4*)(W2 + sub * 8);
    float4 w23 = *(const float4*)(W2 + sub * 8 + 4);
    for (int it = 0; it < 8; ++it) {
        int dl = wave * 8 + it;
        int nd = b * NPB + dl;
        if (nd >= n) break;
        int p1 = (int)offs[dl + 1];
        float a0 = 0.f, a1 = 0.f, a2 = 0.f, a3 = 0.f;
        for (int p = (int)offs[dl] + grp; p < p1; p += 4) {
            unsigned srcn = sorted[p] & 0xFFFFFFu;
            f16x4 v = *(const f16x4*)(h1s + (size_t)srcn * HID + sub * 4);
            a0 += (float)v[0]; a1 += (float)v[1]; a2 += (float)v[2]; a3 += (float)v[3];
        }
        a0 += __shfl_xor(a0, 16); a0 += __shfl_xor(a0, 32);
        a1 += __shfl_xor(a1, 16); a1 += __shfl_xor(a1, 32);
        a2 += __shfl_xor(a2, 16); a2 += __shfl_xor(a2, 32);
        a3 += __shfl_xor(a3, 16); a3 += __shfl_xor(a3, 32);
        f16x4 sv = *(const f16x4*)(h1s + (size_t)nd * HID + sub * 4);  // self
        a0 += (float)sv[0]; a1 += (float)sv[1]; a2 += (float)sv[2]; a3 += (float)sv[3];
        float d = dis[nd];
        float v0 = tanhf(fmaf(a0, d, bb.x));
        float v1 = tanhf(fmaf(a1, d, bb.y));
        float v2 = tanhf(fmaf(a2, d, bb.z));
        float v3 = tanhf(fmaf(a3, d, bb.w));
        float s0 = v0 * w01.x + v1 * w01.z + v2 * w23.x + v3 * w23.z;
        float s1 = v0 * w01.y + v1 * w01.w + v2 * w23.y + v3 * w23.w;
        s0 += __shfl_xor(s0, 1); s1 += __shfl_xor(s1, 1);
        s0 += __shfl_xor(s0, 2); s1 += __shfl_xor(s1, 2);
        s0 += __shfl_xor(s0, 4); s1 += __shfl_xor(s1, 4);
        s0 += __shfl_xor(s0, 8); s1 += __shfl_xor(s1, 8);
        if (lane == 0) {
            es[nd * 2 + 0] = s0 * d;        // pre-scaled by dis for layer-2
            es[nd * 2 + 1] = s1 * d;
        }
    }
}

// ---- layer-2: per-node segment walk + tanh + classifier + sigmoid ------
__global__ void __launch_bounds__(128) k_pass2b(
        const unsigned* __restrict__ pairs, const unsigned* __restrict__ offsG,
        const float* __restrict__ es, const float* __restrict__ dis,
        const float* __restrict__ b2, const float* __restrict__ Wc,
        const float* __restrict__ bc, float* __restrict__ out, int n) {
    int t = threadIdx.x, b = blockIdx.x;
    int nd = b * NPB + t;
    if (nd >= n) return;
    const unsigned* seg = pairs + (size_t)b * CAP;
    int p0 = (int)offsG[(size_t)b * (NPB + 1) + t];
    int p1 = (int)offsG[(size_t)b * (NPB + 1) + t + 1];
    float2 self = *(const float2*)(es + (size_t)nd * 2);
    float a0 = self.x, a1 = self.y;
    for (int p = p0; p < p1; ++p) {
        unsigned srcn = seg[p] & 0xFFFFFFu;
        float2 v = *(const float2*)(es + (size_t)srcn * 2);
        a0 += v.x; a1 += v.y;
    }
    float d = dis[nd];
    float e0 = tanhf(fmaf(a0, d, b2[0]));
    float e1 = tanhf(fmaf(a1, d, b2[1]));
    float z = fmaf(e0, Wc[0], fmaf(e1, Wc[1], bc[0]));
    out[nd] = 1.f / (1.f + expf(-z));
}

extern "C" void kernel_launch(void* const* d_in, const int* in_sizes, int n_in,
                              void* d_out, int out_size, void* d_ws, size_t ws_size,
                              hipStream_t stream) {
    const float* x  = (const float*)d_in[0];
    const int*   ei = (const int*)d_in[1];   // [2, E] as int32
    const float* W1 = (const float*)d_in[2];
    const float* b1 = (const float*)d_in[3];
    const float* W2 = (const float*)d_in[4];
    const float* b2 = (const float*)d_in[5];
    const float* Wc = (const float*)d_in[6];
    const float* bc = (const float*)d_in[7];

    const int n = in_sizes[0] / IN_DIM;
    const int E = in_sizes[1] / 2;
    const int* row = ei;
    const int* col = ei + E;
    const int nbuk = (n + NPB - 1) / NPB;    // 782 for n=100000 (<=1024)

    // workspace layout, 512B-aligned slices; cnt/bCur/gOvf adjacent -> one memset
    char* w = (char*)d_ws;
    auto alloc = [&](size_t bytes) {
        char* p = w;
        w += (bytes + 511) & ~(size_t)511;
        return p;
    };
    int*      cnt   = (int*)alloc((size_t)n * 4 + (size_t)nbuk * 4 + 4 + 8);
    unsigned* bCur  = (unsigned*)(cnt + n);
    unsigned* gOvf  = bCur + nbuk;
    float*    dis   = (float*)alloc((size_t)n * 4);
    ushort*   W1p   = (ushort*)alloc(16 * 64 * 8 * 2);
    unsigned* ovfPk = (unsigned*)alloc((size_t)OVFCAP * 4);
    unsigned* ovfB  = (unsigned*)alloc((size_t)OVFCAP * 4);
    unsigned* pairs = (unsigned*)alloc((size_t)nbuk * CAP * 4);
    unsigned* offsG = (unsigned*)alloc((size_t)nbuk * (NPB + 1) * 4);
    _Float16* h1s   = (_Float16*)alloc((size_t)n * HID * 2);
    float*    es    = (float*)alloc((size_t)n * 2 * 4);

    hipMemsetAsync(cnt, 0, ((size_t)n + nbuk + 1) * 4, stream);

    k_binpairs<<<(E + CHUNK - 1) / CHUNK, 1024, 0, stream>>>(
        row, col, cnt, bCur, pairs, gOvf, ovfPk, ovfB, E, nbuk);
    k_dis<<<(n + 255) / 256, 256, 0, stream>>>(cnt, dis, n);
    k_packW<<<32, 256, 0, stream>>>(W1, W1p);
    k_gemm1<<<(n + 63) / 64, 256, 0, stream>>>(x, W1p, dis, h1s, n);
    k_pass2<<<nbuk, 1024, 0, stream>>>(pairs, bCur, h1s, dis, b1, W2,
                                       gOvf, ovfPk, ovfB, es, offsG, n);
    k_pass2b<<<nbuk, 128, 0, stream>>>(pairs, offsG, es, dis, b2, Wc, bc,
                                       (float*)d_out, n);
}

// Round 7
// 124.546 us; speedup vs baseline: 6.4251x; 1.4130x over previous
//
#include <hip/hip_runtime.h>
#include <math.h>

#define IN_DIM 128
#define HID 64
#define NPB 128            // nodes per bucket
#define NPB_SH 7
#define CAP 4096           // sorted-pairs capacity per bucket (mean 2048)
#define CHUNK 2048         // edges per binning block
#define CPT 2              // CHUNK / 1024

typedef __attribute__((ext_vector_type(8))) short bf16x8;
typedef __attribute__((ext_vector_type(4))) float f32x4;
typedef __attribute__((ext_vector_type(4))) _Float16 f16x4;

static __device__ inline short f2bf(float f) {
    unsigned u = __float_as_uint(f);
    u += 0x7fff + ((u >> 16) & 1);          // RNE
    return (short)(u >> 16);
}

// block-wide exclusive scan (1024 threads, m <= 1024), shfl-based, 2 barriers.
// caller must __syncthreads() before reading out[] written by other threads.
__device__ __forceinline__ void scanExcl1024(const unsigned* in, unsigned* out,
                                             int m, int t, unsigned* wsum) {
    unsigned v = (t < m) ? in[t] : 0u;
    unsigned incl = v;
    int lane = t & 63;
#pragma unroll
    for (int off = 1; off < 64; off <<= 1) {
        unsigned u = __shfl_up(incl, off, 64);
        if (lane >= off) incl += u;
    }
    if (lane == 63) wsum[t >> 6] = incl;
    __syncthreads();
    if (t < 16) {
        unsigned w = wsum[t];
        unsigned winc = w;
#pragma unroll
        for (int off = 1; off < 16; off <<= 1) {
            unsigned u = __shfl_up(winc, off, 64);
            if (t >= off) winc += u;
        }
        wsum[t] = winc - w;                 // exclusive wave base
    }
    __syncthreads();
    if (t < m) out[t] = incl - v + wsum[t >> 6];
}

// ------- pack W1 [128][64] f32 -> bf16 MFMA B-fragment order -------------
__global__ void k_packW(const float* __restrict__ W1, ushort* __restrict__ W1p) {
    int idx = blockIdx.x * 256 + threadIdx.x;        // 0..8191
    int i = idx & 7, lane = (idx >> 3) & 63, fb = (idx >> 9) & 3, kc = (idx >> 11) & 3;
    int k = kc * 32 + (lane >> 4) * 8 + i;
    int f = fb * 16 + (lane & 15);
    W1p[idx] = (ushort)f2bf(W1[k * HID + f]);
}

// ---- binning: chunk-local counting-sort by bucket; contiguous writes ----
// no global atomics; per-block bucket offsets stored in chk (ushort).
__global__ void __launch_bounds__(1024) k_binpairs(
        const int* __restrict__ row, const int* __restrict__ col,
        unsigned* __restrict__ pairsA, unsigned short* __restrict__ chk,
        int E, int nbuk) {
    __shared__ unsigned cntL[1024];
    __shared__ unsigned offs[1024];
    __shared__ unsigned wsum[16];
    __shared__ unsigned stage[CHUNK];
    int t = threadIdx.x;
    int base = blockIdx.x * CHUNK;
    int cc = min(CHUNK, E - base);

    cntL[t] = 0;
    __syncthreads();

    unsigned myPk[CPT], myR[CPT];
    int myB[CPT];
#pragma unroll
    for (int i = 0; i < CPT; ++i) {
        int j = i * 1024 + t;
        myB[i] = -1;
        if (j < cc) {
            int r = row[base + j], c = col[base + j];
            int b = c >> NPB_SH;
            myR[i] = atomicAdd(&cntL[b], 1u);
            myPk[i] = (unsigned)r | ((unsigned)(c & (NPB - 1)) << 24);
            myB[i] = b;
        }
    }
    __syncthreads();
    scanExcl1024(cntL, offs, nbuk, t, wsum);
    __syncthreads();
#pragma unroll
    for (int i = 0; i < CPT; ++i)
        if (myB[i] >= 0) stage[offs[myB[i]] + myR[i]] = myPk[i];
    __syncthreads();
    for (int j = t; j < cc; j += 1024) pairsA[base + j] = stage[j];
    size_t rb = (size_t)blockIdx.x * (nbuk + 1);
    if (t < nbuk) chk[rb + t] = (unsigned short)offs[t];
    if (t == 0) chk[rb + nbuk] = (unsigned short)cc;
}

// ---- per-bucket: collect slices, counting-sort by dst-local, emit -------
// also derives in-degree per node -> dis (no global atomics anywhere).
__global__ void __launch_bounds__(1024) k_sort(
        const unsigned* __restrict__ pairsA, const unsigned short* __restrict__ chk,
        unsigned* __restrict__ pairs2, unsigned* __restrict__ offsG,
        float* __restrict__ dis, int nblk, int nbuk, int n) {
    __shared__ unsigned cntB[1024];
    __shared__ unsigned baseB[1024];
    __shared__ unsigned wsum[16];
    __shared__ unsigned stage[CAP];
    __shared__ unsigned sorted[CAP];
    __shared__ unsigned cntN[NPB];
    __shared__ unsigned offsN[NPB];
    __shared__ unsigned cur[NPB];
    __shared__ unsigned totS;
    int t = threadIdx.x, b = blockIdx.x;

    unsigned s = 0, cntT = 0;
    if (t < nblk) {
        size_t rb = (size_t)t * (nbuk + 1);
        s = chk[rb + b];
        cntT = chk[rb + b + 1] - s;
    }
    cntB[t] = cntT;
    __syncthreads();
    scanExcl1024(cntB, baseB, nblk, t, wsum);
    __syncthreads();
    if (t == 0) totS = baseB[nblk - 1] + cntB[nblk - 1];
    if (t < NPB) cntN[t] = 0;
    if (t < nblk && cntT) {                  // copy my chunk's slice
        unsigned dst = baseB[t];
        const unsigned* sp = pairsA + (size_t)t * CHUNK + s;
        for (unsigned k = 0; k < cntT; ++k)
            if (dst + k < CAP) stage[dst + k] = sp[k];
    }
    __syncthreads();
    int cbt = (int)min(totS, (unsigned)CAP);
    for (int i = t; i < cbt; i += 1024) atomicAdd(&cntN[stage[i] >> 24], 1u);
    __syncthreads();
    scanExcl1024(cntN, offsN, NPB, t, wsum);
    __syncthreads();
    if (t < NPB) cur[t] = offsN[t];
    __syncthreads();
    for (int i = t; i < cbt; i += 1024) {
        unsigned pk = stage[i];
        sorted[atomicAdd(&cur[pk >> 24], 1u)] = pk;
    }
    __syncthreads();
    for (int i = t; i < cbt; i += 1024) pairs2[(size_t)b * CAP + i] = sorted[i];
    if (t <= NPB) offsG[(size_t)b * (NPB + 1) + t] = (t < NPB) ? offsN[t] : (unsigned)cbt;
    int nd = b * NPB + t;
    if (t < NPB && nd < n) dis[nd] = rsqrtf((float)(cntN[t] + 1));  // +1 self-loop
}

// ------- h1s = (x @ W1) * dis[node]  via bf16 MFMA, fp16 output ----------
__global__ void __launch_bounds__(256) k_gemm1(const float* __restrict__ x,
                                               const ushort* __restrict__ W1p,
                                               const float* __restrict__ dis,
                                               _Float16* __restrict__ h1s, int n) {
    int t = threadIdx.x, wave = t >> 6, lane = t & 63;
    int nb = blockIdx.x * 64 + wave * 16;
    int arow = nb + (lane & 15);            // A: row = lane&15
    int g = lane >> 4;                      // k-group
    const bf16x8* Wp = (const bf16x8*)W1p;

    f32x4 acc0 = {0.f, 0.f, 0.f, 0.f}, acc1 = acc0, acc2 = acc0, acc3 = acc0;

#pragma unroll
    for (int kc = 0; kc < 4; ++kc) {
        bf16x8 a;
        if (arow < n) {
            const float4* xp = (const float4*)(x + (size_t)arow * IN_DIM + kc * 32 + g * 8);
            float4 x0 = xp[0], x1 = xp[1];
            a[0] = f2bf(x0.x); a[1] = f2bf(x0.y); a[2] = f2bf(x0.z); a[3] = f2bf(x0.w);
            a[4] = f2bf(x1.x); a[5] = f2bf(x1.y); a[6] = f2bf(x1.z); a[7] = f2bf(x1.w);
        } else {
            for (int i = 0; i < 8; ++i) a[i] = 0;
        }
        acc0 = __builtin_amdgcn_mfma_f32_16x16x32_bf16(a, Wp[(kc * 4 + 0) * 64 + lane], acc0, 0, 0, 0);
        acc1 = __builtin_amdgcn_mfma_f32_16x16x32_bf16(a, Wp[(kc * 4 + 1) * 64 + lane], acc1, 0, 0, 0);
        acc2 = __builtin_amdgcn_mfma_f32_16x16x32_bf16(a, Wp[(kc * 4 + 2) * 64 + lane], acc2, 0, 0, 0);
        acc3 = __builtin_amdgcn_mfma_f32_16x16x32_bf16(a, Wp[(kc * 4 + 3) * 64 + lane], acc3, 0, 0, 0);
    }

    // D: col = lane&15, row = (lane>>4)*4 + reg
    int c = lane & 15, rbase = g * 4;
    float dn[4];
    int nd[4];
#pragma unroll
    for (int r = 0; r < 4; ++r) {
        nd[r] = nb + rbase + r;
        dn[r] = (nd[r] < n) ? dis[nd[r]] : 0.f;
    }
#define EPI(FB, ACC)                                                          \
    {                                                                         \
        int f = FB * 16 + c;                                                  \
        _Pragma("unroll") for (int r = 0; r < 4; ++r) {                       \
            if (nd[r] < n)                                                    \
                h1s[(size_t)nd[r] * HID + f] = (_Float16)(ACC[r] * dn[r]);    \
        }                                                                     \
    }
    EPI(0, acc0) EPI(1, acc1) EPI(2, acc2) EPI(3, acc3)
#undef EPI
}

// ---- layer-1 gather: LDS-staged sorted pairs, register accumulation -----
__global__ void __launch_bounds__(1024) k_gather1(
        const unsigned* __restrict__ pairs2, const unsigned* __restrict__ offsG,
        const _Float16* __restrict__ h1s, const float* __restrict__ dis,
        const float* __restrict__ b1, const float* __restrict__ W2,
        float* __restrict__ es, int n) {
    __shared__ unsigned sorted[CAP];
    __shared__ unsigned offs[NPB + 1];
    int t = threadIdx.x, b = blockIdx.x;
    if (t <= NPB) offs[t] = offsG[(size_t)b * (NPB + 1) + t];
    __syncthreads();
    int cbt = (int)offs[NPB];
    for (int i = t; i < cbt; i += 1024) sorted[i] = pairs2[(size_t)b * CAP + i];
    __syncthreads();

    // 16 waves x 8 nodes; 4 edge-groups x 16 feature-lanes per wave
    int wave = t >> 6, lane = t & 63;
    int grp = lane >> 4, sub = lane & 15;
    float4 bb  = *(const float4*)(b1 + sub * 4);
    float4 w01 = *(const float4*)(W2 + sub * 8);
    float4 w23 = *(const float4*)(W2 + sub * 8 + 4);
    for (int it = 0; it < 8; ++it) {
        int dl = wave * 8 + it;
        int nd = b * NPB + dl;
        if (nd >= n) break;
        int p1 = (int)offs[dl + 1];
        float a0 = 0.f, a1 = 0.f, a2 = 0.f, a3 = 0.f;
        for (int p = (int)offs[dl] + grp; p < p1; p += 4) {
            unsigned srcn = sorted[p] & 0xFFFFFFu;
            f16x4 v = *(const f16x4*)(h1s + (size_t)srcn * HID + sub * 4);
            a0 += (float)v[0]; a1 += (float)v[1]; a2 += (float)v[2]; a3 += (float)v[3];
        }
        a0 += __shfl_xor(a0, 16); a0 += __shfl_xor(a0, 32);
        a1 += __shfl_xor(a1, 16); a1 += __shfl_xor(a1, 32);
        a2 += __shfl_xor(a2, 16); a2 += __shfl_xor(a2, 32);
        a3 += __shfl_xor(a3, 16); a3 += __shfl_xor(a3, 32);
        f16x4 sv = *(const f16x4*)(h1s + (size_t)nd * HID + sub * 4);  // self
        a0 += (float)sv[0]; a1 += (float)sv[1]; a2 += (float)sv[2]; a3 += (float)sv[3];
        float d = dis[nd];
        float v0 = tanhf(fmaf(a0, d, bb.x));
        float v1 = tanhf(fmaf(a1, d, bb.y));
        float v2 = tanhf(fmaf(a2, d, bb.z));
        float v3 = tanhf(fmaf(a3, d, bb.w));
        float s0 = v0 * w01.x + v1 * w01.z + v2 * w23.x + v3 * w23.z;
        float s1 = v0 * w01.y + v1 * w01.w + v2 * w23.y + v3 * w23.w;
        s0 += __shfl_xor(s0, 1); s1 += __shfl_xor(s1, 1);
        s0 += __shfl_xor(s0, 2); s1 += __shfl_xor(s1, 2);
        s0 += __shfl_xor(s0, 4); s1 += __shfl_xor(s1, 4);
        s0 += __shfl_xor(s0, 8); s1 += __shfl_xor(s1, 8);
        if (lane == 0) {
            es[nd * 2 + 0] = s0 * d;        // pre-scaled by dis for layer-2
            es[nd * 2 + 1] = s1 * d;
        }
    }
}

// ---- layer-2: per-node segment walk + tanh + classifier + sigmoid ------
__global__ void __launch_bounds__(128) k_pass2b(
        const unsigned* __restrict__ pairs2, const unsigned* __restrict__ offsG,
        const float* __restrict__ es, const float* __restrict__ dis,
        const float* __restrict__ b2, const float* __restrict__ Wc,
        const float* __restrict__ bc, float* __restrict__ out, int n) {
    int t = threadIdx.x, b = blockIdx.x;
    int nd = b * NPB + t;
    if (nd >= n) return;
    const unsigned* seg = pairs2 + (size_t)b * CAP;
    int p0 = (int)offsG[(size_t)b * (NPB + 1) + t];
    int p1 = (int)offsG[(size_t)b * (NPB + 1) + t + 1];
    float2 self = *(const float2*)(es + (size_t)nd * 2);
    float a0 = self.x, a1 = self.y;
    for (int p = p0; p < p1; ++p) {
        unsigned srcn = seg[p] & 0xFFFFFFu;
        float2 v = *(const float2*)(es + (size_t)srcn * 2);
        a0 += v.x; a1 += v.y;
    }
    float d = dis[nd];
    float e0 = tanhf(fmaf(a0, d, b2[0]));
    float e1 = tanhf(fmaf(a1, d, b2[1]));
    float z = fmaf(e0, Wc[0], fmaf(e1, Wc[1], bc[0]));
    out[nd] = 1.f / (1.f + expf(-z));
}

extern "C" void kernel_launch(void* const* d_in, const int* in_sizes, int n_in,
                              void* d_out, int out_size, void* d_ws, size_t ws_size,
                              hipStream_t stream) {
    const float* x  = (const float*)d_in[0];
    const int*   ei = (const int*)d_in[1];   // [2, E] as int32
    const float* W1 = (const float*)d_in[2];
    const float* b1 = (const float*)d_in[3];
    const float* W2 = (const float*)d_in[4];
    const float* b2 = (const float*)d_in[5];
    const float* Wc = (const float*)d_in[6];
    const float* bc = (const float*)d_in[7];

    const int n = in_sizes[0] / IN_DIM;
    const int E = in_sizes[1] / 2;
    const int* row = ei;
    const int* col = ei + E;
    const int nbuk = (n + NPB - 1) / NPB;        // 782 (<=1024)
    const int nblk = (E + CHUNK - 1) / CHUNK;    // 782 (<=1024)

    // workspace layout, 512B-aligned slices
    char* w = (char*)d_ws;
    auto alloc = [&](size_t bytes) {
        char* p = w;
        w += (bytes + 511) & ~(size_t)511;
        return p;
    };
    unsigned*       pairsA = (unsigned*)alloc((size_t)nblk * CHUNK * 4);
    unsigned short* chk    = (unsigned short*)alloc((size_t)nblk * (nbuk + 1) * 2);
    unsigned*       pairs2 = (unsigned*)alloc((size_t)nbuk * CAP * 4);
    unsigned*       offsG  = (unsigned*)alloc((size_t)nbuk * (NPB + 1) * 4);
    float*          dis    = (float*)alloc((size_t)n * 4);
    ushort*         W1p    = (ushort*)alloc(16 * 64 * 8 * 2);
    _Float16*       h1s    = (_Float16*)alloc((size_t)n * HID * 2);
    float*          es     = (float*)alloc((size_t)n * 2 * 4);

    k_packW   <<<32, 256, 0, stream>>>(W1, W1p);
    k_binpairs<<<nblk, 1024, 0, stream>>>(row, col, pairsA, chk, E, nbuk);
    k_sort    <<<nbuk, 1024, 0, stream>>>(pairsA, chk, pairs2, offsG, dis,
                                          nblk, nbuk, n);
    k_gemm1   <<<(n + 63) / 64, 256, 0, stream>>>(x, W1p, dis, h1s, n);
    k_gather1 <<<nbuk, 1024, 0, stream>>>(pairs2, offsG, h1s, dis, b1, W2, es, n);
    k_pass2b  <<<nbuk, 128, 0, stream>>>(pairs2, offsG, es, dis, b2, Wc, bc,
                                         (float*)d_out, n);
}